// Round 5
// baseline (361.051 us; speedup 1.0000x reference)
//
#include <hip/hip_runtime.h>
#include <stdint.h>
#include <stddef.h>

typedef __bf16 bf16;
typedef __bf16 bf16x8 __attribute__((ext_vector_type(8)));
typedef __bf16 bf16x4 __attribute__((ext_vector_type(4)));
typedef float f32x4 __attribute__((ext_vector_type(4)));

static_assert(sizeof(bf16x8) == 16, "bf16x8 must be 16B");

__device__ __forceinline__ void gload_lds16(const void* g, void* l) {
    __builtin_amdgcn_global_load_lds(
        (const __attribute__((address_space(1))) uint32_t*)g,
        (__attribute__((address_space(3))) uint32_t*)l, 16, 0, 0);
}

// ---------------------------------------------------------------------------
// Kernel 1: fused transpose + attention.
// blocks 0..511: transpose x[b][ci][y][x] fp32 -> xt[b][y][cg(32)][x(64)][c8] bf16
// blocks 512..519: attention, wave-parallel dot products (coalesced w1 reads)
// ---------------------------------------------------------------------------
__global__ void prep_kernel(const float* __restrict__ x, bf16* __restrict__ xt,
                            const float* __restrict__ sk,
                            const float* __restrict__ w1,
                            const float* __restrict__ w2,
                            float* __restrict__ att) {
    __shared__ bf16 T[256 * 64];     // transpose staging (32 KB)
    __shared__ float pooled[784];
    __shared__ float hdn[196];
    __shared__ float logits[16];
    const int t = threadIdx.x;

    if (blockIdx.x < 512) {
        const int bid = blockIdx.x;
        const int b = bid >> 6, y = bid & 63;
        const float* src = x + (size_t)b * 256 * 4096 + (size_t)y * 64;
        for (int i = 0; i < 16; ++i) {
            int v = t + 256 * i;              // 4096 float4 chunks
            int ci = v >> 4, x4 = (v & 15) * 4;
            float4 f = *(const float4*)(src + (size_t)ci * 4096 + x4);
            bf16* d = &T[ci * 64 + x4];
            d[0] = (bf16)f.x; d[1] = (bf16)f.y; d[2] = (bf16)f.z; d[3] = (bf16)f.w;
        }
        __syncthreads();
        bf16* dstb = xt + (size_t)bid * 16384;
        for (int i = 0; i < 8; ++i) {
            int c2 = t + 256 * i;             // 2048 16B chunks: [cg][x]
            int cg = c2 >> 6, xx = c2 & 63;
            bf16x8 v;
#pragma unroll
            for (int c = 0; c < 8; ++c) v[c] = T[(cg * 8 + c) * 64 + xx];
            *(bf16x8*)(dstb + (size_t)c2 * 8) = v;
        }
    } else {
        const int b = blockIdx.x - 512;
        const int wave = t >> 6, lane = t & 63;
        const float* skb = sk + (size_t)b * 3136;
        for (int e = t; e < 784; e += 256) {
            int oy = e / 28, ox = e % 28;
            const float* p = skb + (oy * 2) * 56 + ox * 2;
            pooled[e] = 0.25f * (p[0] + p[1] + p[56] + p[57]);
        }
        __syncthreads();
        // layer 1: 196 dots of length 784; lanes split the sum (coalesced)
        for (int j = wave; j < 196; j += 4) {
            const float* wr = w1 + (size_t)j * 784;
            float s = 0.f;
            for (int i = lane; i < 784; i += 64) s += pooled[i] * wr[i];
#pragma unroll
            for (int off = 32; off; off >>= 1) s += __shfl_down(s, off, 64);
            if (lane == 0) hdn[j] = s > 0.f ? s : 0.f;
        }
        __syncthreads();
        // layer 2: 16 dots of length 196
        for (int j = wave; j < 16; j += 4) {
            const float* wr = w2 + (size_t)j * 196;
            float s = 0.f;
            for (int i = lane; i < 196; i += 64) s += hdn[i] * wr[i];
#pragma unroll
            for (int off = 32; off; off >>= 1) s += __shfl_down(s, off, 64);
            if (lane == 0) logits[j] = s * (1.0f / 30.0f);
        }
        __syncthreads();
        if (t == 0) {
            float m = logits[0];
            for (int k = 1; k < 16; ++k) m = fmaxf(m, logits[k]);
            float e16[16], sum = 0.f;
            for (int k = 0; k < 16; ++k) { e16[k] = expf(logits[k] - m); sum += e16[k]; }
            float inv = 1.f / sum;
            for (int k = 0; k < 16; ++k) att[b * 16 + k] = e16[k] * inv;
        }
    }
}

// ---------------------------------------------------------------------------
// Kernel 2: weight aggregation + bias aggregation.
// grid = 1024 (chunk-major: co = bid&255, chunk = bid>>8), block = 256.
// agg_w2 layout: [b][pos][chunk(4)][half(2)][cg(8)][co_l(128)][c8(8)]  bf16
// ---------------------------------------------------------------------------
__global__ __launch_bounds__(256) void agg_kernel(
    const float* __restrict__ weight,
    const float* __restrict__ bias,
    const float* __restrict__ att,
    bf16* __restrict__ aggw,
    float* __restrict__ aggb) {
    const int bid = blockIdx.x;
    const int co = bid & 255, chunk = bid >> 8;
    const int t = threadIdx.x;

    __shared__ bf16 accW[8 * 576];  // [b][el]  (el = local e within chunk)

    if (chunk == 0 && t < 8) {
        float s = 0.f;
        for (int k = 0; k < 16; ++k) s += att[t * 16 + k] * bias[k * 256 + co];
        aggb[t * 256 + co] = s;
    }

    if (t < 144) {
        const float* wbase = weight + (size_t)co * 2304 + (size_t)chunk * 576 + (size_t)t * 4;
        float4 wv[16];
#pragma unroll
        for (int k = 0; k < 16; ++k)
            wv[k] = *(const float4*)(wbase + (size_t)k * 589824);
        float a[8][4];
#pragma unroll
        for (int b = 0; b < 8; ++b)
#pragma unroll
            for (int j = 0; j < 4; ++j) a[b][j] = 0.f;
#pragma unroll
        for (int k = 0; k < 16; ++k) {
#pragma unroll
            for (int b = 0; b < 8; ++b) {
                const float av = att[b * 16 + k];  // uniform -> scalar load
                a[b][0] += av * wv[k].x;
                a[b][1] += av * wv[k].y;
                a[b][2] += av * wv[k].z;
                a[b][3] += av * wv[k].w;
            }
        }
#pragma unroll
        for (int b = 0; b < 8; ++b) {
            bf16x4 v;
#pragma unroll
            for (int j = 0; j < 4; ++j) v[j] = (bf16)a[b][j];
            *(bf16x4*)&accW[b * 576 + t * 4] = v;
        }
    }
    __syncthreads();

    // write out in the conv-native layout
    const int half = co >> 7, co_l = co & 127;
    for (int s = t; s < 576; s += 256) {
        const int b = s / 72, r = s - b * 72;
        const int pos = r >> 3, cg = r & 7;
        bf16x8 v;
#pragma unroll
        for (int c = 0; c < 8; ++c) v[c] = accW[b * 576 + (cg * 8 + c) * 9 + pos];
        size_t o = (((((size_t)b * 9 + pos) * 4 + chunk) * 2 + half) * 8 + cg) * 128 + co_l;
        *(bf16x8*)(aggw + o * 8) = v;
    }
}

// ---------------------------------------------------------------------------
// Kernel 3: implicit-GEMM conv + bias + residual.
// grid = 512: bid = [b(8)][half(2)][ytile(32)], block = 256 (4 waves, 2x2).
// Block tile: 128 co x (2 rows x 64 cols).
// KEY (r5): A (weights) global->VGPR, register-double-buffered, prefetched
// one tap ahead — W never touches LDS (halves LDS read traffic, removes all
// W DMA writes; r2/r4 were LDS-BW-bound). X double-buffered in LDS, staged
// once per ci-chunk with 9 taps of DMA flight. Barriers: 4 total (vs 72).
// Occupancy preserved: LDS 66 KB -> 2 blocks/CU = 2 waves/SIMD.
// ---------------------------------------------------------------------------
__global__ __launch_bounds__(256, 2) void conv_kernel(
    const bf16* __restrict__ xt, const bf16* __restrict__ aggw,
    const float* __restrict__ aggb, const float* __restrict__ xin,
    float* __restrict__ out) {
    const int bid = blockIdx.x;
    const int ytile = bid & 31;
    const int half = (bid >> 5) & 1;
    const int b = bid >> 6;
    const int tid = threadIdx.x;
    const int wave = tid >> 6, lane = tid & 63;
    const int wm = wave & 1, wn = wave >> 1;
    const int lane15 = lane & 15, quad = lane >> 4;

    // [buf][row(4)][cg(8)][col(66: 0/65 zero halo)][c8]  = 2 x 33 KB
    __shared__ __align__(16) bf16 Xs[2][4][8][66][8];

    f32x4 acc[4][4];
#pragma unroll
    for (int mt = 0; mt < 4; ++mt)
#pragma unroll
        for (int nt = 0; nt < 4; ++nt) acc[mt][nt] = f32x4{0.f, 0.f, 0.f, 0.f};

    // zero both X buffers once (halo cols + out-of-image rows stay 0)
    {
        uint4 z; z.x = z.y = z.z = z.w = 0u;
        uint4* p = (uint4*)&Xs[0][0][0][0][0];
        for (int i = tid; i < 4224; i += 256) p[i] = z;
    }

    const int yrow = ytile * 2 - 1 + wave;          // wave w stages halo row w
    const bool rowok = (yrow >= 0) && (yrow < 64);
    const bf16* xsrc = xt + ((size_t)b * 64 + (rowok ? yrow : 0)) * 16384 + (size_t)lane * 8;

    auto stageX = [&](int chunk, int buf) {
        if (rowok) {
            const bf16* s0 = xsrc + (size_t)chunk * 4096;
            bf16* d0 = &Xs[buf][wave][0][1][0];
#pragma unroll
            for (int cg = 0; cg < 8; ++cg)
                gload_lds16(s0 + cg * 512, d0 + cg * 528);
        }
    };

    bf16x8 afr[2][8];
    auto loadA = [&](int par, int chunk, int pos) {
        const bf16* ab = aggw + ((((size_t)b * 9 + pos) * 4 + chunk) * 2 + half) * 8192;
#pragma unroll
        for (int s = 0; s < 2; ++s)
#pragma unroll
            for (int mt = 0; mt < 4; ++mt)
                afr[par][s * 4 + mt] = *(const bf16x8*)(
                    ab + (size_t)((s * 4 + quad) * 128 + wm * 64 + mt * 16 + lane15) * 8);
    };

    __syncthreads();            // zeros committed before any DMA
    stageX(0, 0);
    loadA(0, 0, 0);
    __syncthreads();            // X chunk0 in LDS

    for (int chunk = 0; chunk < 4; ++chunk) {
        const int xb = chunk & 1;
#pragma unroll
        for (int pos = 0; pos < 9; ++pos) {
            const int par = (chunk + pos) & 1;
            if (!(chunk == 3 && pos == 8)) {        // reg-prefetch A(t+1), no barrier
                const int nc = (pos == 8) ? chunk + 1 : chunk;
                const int np = (pos == 8) ? 0 : pos + 1;
                loadA(par ^ 1, nc, np);
            }
            if (pos == 0 && chunk < 3) stageX(chunk + 1, xb ^ 1);  // 9 taps of flight
            const int kh = pos / 3, kw = pos - kh * 3;
            const int xr = wn + kh;
#pragma unroll
            for (int s = 0; s < 2; ++s) {
                const int cg = s * 4 + quad;
                bf16x8 bfr[4];
#pragma unroll
                for (int nt = 0; nt < 4; ++nt)
                    bfr[nt] = *(const bf16x8*)&Xs[xb][xr][cg][kw + nt * 16 + lane15][0];
#pragma unroll
                for (int mt = 0; mt < 4; ++mt)
#pragma unroll
                    for (int nt = 0; nt < 4; ++nt)
                        acc[mt][nt] = __builtin_amdgcn_mfma_f32_16x16x32_bf16(
                            afr[par][s * 4 + mt], bfr[nt], acc[mt][nt], 0, 0, 0);
            }
        }
        if (chunk < 3) __syncthreads();  // readers of Xs[xb] done; next-X DMA drained
    }

    // epilogue: conv + agg_b + residual, fp32 out
    const int y = ytile * 2 + wn;
#pragma unroll
    for (int mt = 0; mt < 4; ++mt) {
#pragma unroll
        for (int r = 0; r < 4; ++r) {
            const int co = half * 128 + wm * 64 + mt * 16 + quad * 4 + r;
            const float bbv = aggb[b * 256 + co];
            const size_t rowbase = (((size_t)b * 256 + co) * 64 + y) * 64;
#pragma unroll
            for (int nt = 0; nt < 4; ++nt) {
                const size_t oidx = rowbase + nt * 16 + lane15;
                out[oidx] = acc[mt][nt][r] + bbv + xin[oidx];
            }
        }
    }
}

// ---------------------------------------------------------------------------
extern "C" void kernel_launch(void* const* d_in, const int* in_sizes, int n_in,
                              void* d_out, int out_size, void* d_ws, size_t ws_size,
                              hipStream_t stream) {
    const float* x    = (const float*)d_in[0];  // [8,256,64,64]
    const float* sk   = (const float*)d_in[1];  // [8,1,56,56]
    const float* wgt  = (const float*)d_in[2];  // [16,256,256,3,3]
    const float* bias = (const float*)d_in[3];  // [16,256]
    const float* w1   = (const float*)d_in[4];  // [196,784]
    const float* w2   = (const float*)d_in[5];  // [16,196]
    float* out = (float*)d_out;

    char* ws = (char*)d_ws;
    float* att  = (float*)(ws + 0);                      // 512 B
    float* aggb = (float*)(ws + 1024);                   // 8 KB
    bf16*  aggw = (bf16*)(ws + 16384);                   // 9,437,184 B
    bf16*  xt   = (bf16*)(ws + 16384 + 9437184);         // 16,777,216 B

    prep_kernel<<<520, 256, 0, stream>>>(x, xt, sk, w1, w2, att);
    agg_kernel<<<1024, 256, 0, stream>>>(wgt, bias, att, aggw, aggb);
    conv_kernel<<<512, 256, 0, stream>>>(xt, aggw, aggb, x, out);
}

// Round 6
// 203.167 us; speedup vs baseline: 1.7771x; 1.7771x over previous
//
#include <hip/hip_runtime.h>
#include <stdint.h>
#include <stddef.h>

typedef __bf16 bf16;
typedef __bf16 bf16x8 __attribute__((ext_vector_type(8)));
typedef __bf16 bf16x4 __attribute__((ext_vector_type(4)));
typedef float f32x4 __attribute__((ext_vector_type(4)));

static_assert(sizeof(bf16x8) == 16, "bf16x8 must be 16B");

__device__ __forceinline__ void gload_lds16(const void* g, void* l) {
    __builtin_amdgcn_global_load_lds(
        (const __attribute__((address_space(1))) uint32_t*)g,
        (__attribute__((address_space(3))) uint32_t*)l, 16, 0, 0);
}

__device__ __forceinline__ float dot4(float4 a, float4 b) {
    return a.x * b.x + a.y * b.y + a.z * b.z + a.w * b.w;
}

// ---------------------------------------------------------------------------
// Kernel 1: fused attention + transpose.
// blocks 0..7  : attention (pool 56->28, MLP 784->196->16, softmax/T).
//   Attention blocks come FIRST so they run concurrently with the 512
//   transpose blocks (r5 had them last -> 230 us serial tail).
//   L1 rows are loaded as 4 independent float4s per lane (one latency
//   exposure per row, not 13 serialized scalar loads).
// blocks 8..519: transpose x[b][ci][y][x] fp32 -> xt[b][y][cg(32)][x(64)][c8] bf16
// ---------------------------------------------------------------------------
__global__ void prep_kernel(const float* __restrict__ x, bf16* __restrict__ xt,
                            const float* __restrict__ sk,
                            const float* __restrict__ w1,
                            const float* __restrict__ w2,
                            float* __restrict__ att) {
    __shared__ bf16 T[256 * 64];     // transpose staging (32 KB)
    __shared__ __align__(16) float pooled[784];
    __shared__ float hdn[208];
    __shared__ float logits[16];
    const int t = threadIdx.x;

    if (blockIdx.x >= 8) {
        const int bid = blockIdx.x - 8;
        const int b = bid >> 6, y = bid & 63;
        const float* src = x + (size_t)b * 256 * 4096 + (size_t)y * 64;
        for (int i = 0; i < 16; ++i) {
            int v = t + 256 * i;              // 4096 float4 chunks
            int ci = v >> 4, x4 = (v & 15) * 4;
            float4 f = *(const float4*)(src + (size_t)ci * 4096 + x4);
            bf16* d = &T[ci * 64 + x4];
            d[0] = (bf16)f.x; d[1] = (bf16)f.y; d[2] = (bf16)f.z; d[3] = (bf16)f.w;
        }
        __syncthreads();
        bf16* dstb = xt + (size_t)bid * 16384;
        for (int i = 0; i < 8; ++i) {
            int c2 = t + 256 * i;             // 2048 16B chunks: [cg][x]
            int cg = c2 >> 6, xx = c2 & 63;
            bf16x8 v;
#pragma unroll
            for (int c = 0; c < 8; ++c) v[c] = T[(cg * 8 + c) * 64 + xx];
            *(bf16x8*)(dstb + (size_t)c2 * 8) = v;
        }
    } else {
        const int b = blockIdx.x;
        const int wave = t >> 6, lane = t & 63;
        const float* skb = sk + (size_t)b * 3136;
        for (int e = t; e < 784; e += 256) {
            int oy = e / 28, ox = e % 28;
            const float* p = skb + (oy * 2) * 56 + ox * 2;
            pooled[e] = 0.25f * (p[0] + p[1] + p[56] + p[57]);
        }
        __syncthreads();
        const float4* p4 = (const float4*)pooled;      // 196 float4
        const float m3 = (lane < 4) ? 1.f : 0.f;
        const int i3 = 192 + (lane & 3);
        // layer 1: 196 dots of length 784; 4 independent float4 loads per lane
        for (int j = wave; j < 196; j += 4) {
            const float4* wr4 = (const float4*)(w1 + (size_t)j * 784);
            float4 a0 = wr4[lane];
            float4 a1 = wr4[lane + 64];
            float4 a2 = wr4[lane + 128];
            float4 a3 = wr4[i3];
            float s = dot4(a0, p4[lane]) + dot4(a1, p4[lane + 64])
                    + dot4(a2, p4[lane + 128]) + m3 * dot4(a3, p4[i3]);
#pragma unroll
            for (int off = 32; off; off >>= 1) s += __shfl_down(s, off, 64);
            if (lane == 0) hdn[j] = s > 0.f ? s : 0.f;
        }
        __syncthreads();
        // layer 2: 16 dots of length 196 (49 float4; lanes 0..48 masked)
        const float m2 = (lane < 49) ? 1.f : 0.f;
        const int i2 = (lane < 49) ? lane : 48;
        for (int j = wave; j < 16; j += 4) {
            const float4* wr4 = (const float4*)(w2 + (size_t)j * 196);
            float s = m2 * dot4(wr4[i2], p4[0]);  // placeholder to keep types; recompute below
            // recompute properly against hdn:
            const float4* h4 = (const float4*)hdn;
            s = m2 * dot4(wr4[i2], h4[i2]);
#pragma unroll
            for (int off = 32; off; off >>= 1) s += __shfl_down(s, off, 64);
            if (lane == 0) logits[j] = s * (1.0f / 30.0f);
        }
        __syncthreads();
        if (t == 0) {
            float m = logits[0];
            for (int k = 1; k < 16; ++k) m = fmaxf(m, logits[k]);
            float e16[16], sum = 0.f;
            for (int k = 0; k < 16; ++k) { e16[k] = expf(logits[k] - m); sum += e16[k]; }
            float inv = 1.f / sum;
            for (int k = 0; k < 16; ++k) att[b * 16 + k] = e16[k] * inv;
        }
    }
}

// ---------------------------------------------------------------------------
// Kernel 2: weight aggregation + bias aggregation.
// grid = 1024 (chunk-major: co = bid&255, chunk = bid>>8), block = 256.
// agg_w2 layout: [b][pos][chunk(4)][half(2)][cg(8)][co_l(128)][c8(8)]  bf16
// ---------------------------------------------------------------------------
__global__ __launch_bounds__(256) void agg_kernel(
    const float* __restrict__ weight,
    const float* __restrict__ bias,
    const float* __restrict__ att,
    bf16* __restrict__ aggw,
    float* __restrict__ aggb) {
    const int bid = blockIdx.x;
    const int co = bid & 255, chunk = bid >> 8;
    const int t = threadIdx.x;

    __shared__ bf16 accW[8 * 576];  // [b][el]  (el = local e within chunk)

    if (chunk == 0 && t < 8) {
        float s = 0.f;
        for (int k = 0; k < 16; ++k) s += att[t * 16 + k] * bias[k * 256 + co];
        aggb[t * 256 + co] = s;
    }

    if (t < 144) {
        const float* wbase = weight + (size_t)co * 2304 + (size_t)chunk * 576 + (size_t)t * 4;
        float4 wv[16];
#pragma unroll
        for (int k = 0; k < 16; ++k)
            wv[k] = *(const float4*)(wbase + (size_t)k * 589824);
        float a[8][4];
#pragma unroll
        for (int b = 0; b < 8; ++b)
#pragma unroll
            for (int j = 0; j < 4; ++j) a[b][j] = 0.f;
#pragma unroll
        for (int k = 0; k < 16; ++k) {
#pragma unroll
            for (int b = 0; b < 8; ++b) {
                const float av = att[b * 16 + k];  // uniform -> scalar load
                a[b][0] += av * wv[k].x;
                a[b][1] += av * wv[k].y;
                a[b][2] += av * wv[k].z;
                a[b][3] += av * wv[k].w;
            }
        }
#pragma unroll
        for (int b = 0; b < 8; ++b) {
            bf16x4 v;
#pragma unroll
            for (int j = 0; j < 4; ++j) v[j] = (bf16)a[b][j];
            *(bf16x4*)&accW[b * 576 + t * 4] = v;
        }
    }
    __syncthreads();

    // write out in the conv-native layout
    const int half = co >> 7, co_l = co & 127;
    for (int s = t; s < 576; s += 256) {
        const int b = s / 72, r = s - b * 72;
        const int pos = r >> 3, cg = r & 7;
        bf16x8 v;
#pragma unroll
        for (int c = 0; c < 8; ++c) v[c] = accW[b * 576 + (cg * 8 + c) * 9 + pos];
        size_t o = (((((size_t)b * 9 + pos) * 4 + chunk) * 2 + half) * 8 + cg) * 128 + co_l;
        *(bf16x8*)(aggw + o * 8) = v;
    }
}

// ---------------------------------------------------------------------------
// Kernel 3: implicit-GEMM conv + bias + residual.  (unchanged from r5)
// grid = 512: bid = [b(8)][half(2)][ytile(32)], block = 256 (4 waves, 2x2).
// A (weights) global->VGPR register-double-buffered (no W LDS traffic);
// X double-buffered in LDS, staged once per ci-chunk. 4 barriers total.
// ---------------------------------------------------------------------------
__global__ __launch_bounds__(256, 2) void conv_kernel(
    const bf16* __restrict__ xt, const bf16* __restrict__ aggw,
    const float* __restrict__ aggb, const float* __restrict__ xin,
    float* __restrict__ out) {
    const int bid = blockIdx.x;
    const int ytile = bid & 31;
    const int half = (bid >> 5) & 1;
    const int b = bid >> 6;
    const int tid = threadIdx.x;
    const int wave = tid >> 6, lane = tid & 63;
    const int wm = wave & 1, wn = wave >> 1;
    const int lane15 = lane & 15, quad = lane >> 4;

    // [buf][row(4)][cg(8)][col(66: 0/65 zero halo)][c8]  = 2 x 33 KB
    __shared__ __align__(16) bf16 Xs[2][4][8][66][8];

    f32x4 acc[4][4];
#pragma unroll
    for (int mt = 0; mt < 4; ++mt)
#pragma unroll
        for (int nt = 0; nt < 4; ++nt) acc[mt][nt] = f32x4{0.f, 0.f, 0.f, 0.f};

    // zero both X buffers once (halo cols + out-of-image rows stay 0)
    {
        uint4 z; z.x = z.y = z.z = z.w = 0u;
        uint4* p = (uint4*)&Xs[0][0][0][0][0];
        for (int i = tid; i < 4224; i += 256) p[i] = z;
    }

    const int yrow = ytile * 2 - 1 + wave;          // wave w stages halo row w
    const bool rowok = (yrow >= 0) && (yrow < 64);
    const bf16* xsrc = xt + ((size_t)b * 64 + (rowok ? yrow : 0)) * 16384 + (size_t)lane * 8;

    auto stageX = [&](int chunk, int buf) {
        if (rowok) {
            const bf16* s0 = xsrc + (size_t)chunk * 4096;
            bf16* d0 = &Xs[buf][wave][0][1][0];
#pragma unroll
            for (int cg = 0; cg < 8; ++cg)
                gload_lds16(s0 + cg * 512, d0 + cg * 528);
        }
    };

    bf16x8 afr[2][8];
    auto loadA = [&](int par, int chunk, int pos) {
        const bf16* ab = aggw + ((((size_t)b * 9 + pos) * 4 + chunk) * 2 + half) * 8192;
#pragma unroll
        for (int s = 0; s < 2; ++s)
#pragma unroll
            for (int mt = 0; mt < 4; ++mt)
                afr[par][s * 4 + mt] = *(const bf16x8*)(
                    ab + (size_t)((s * 4 + quad) * 128 + wm * 64 + mt * 16 + lane15) * 8);
    };

    __syncthreads();            // zeros committed before any DMA
    stageX(0, 0);
    loadA(0, 0, 0);
    __syncthreads();            // X chunk0 in LDS

    for (int chunk = 0; chunk < 4; ++chunk) {
        const int xb = chunk & 1;
#pragma unroll
        for (int pos = 0; pos < 9; ++pos) {
            const int par = (chunk + pos) & 1;
            if (!(chunk == 3 && pos == 8)) {        // reg-prefetch A(t+1), no barrier
                const int nc = (pos == 8) ? chunk + 1 : chunk;
                const int np = (pos == 8) ? 0 : pos + 1;
                loadA(par ^ 1, nc, np);
            }
            if (pos == 0 && chunk < 3) stageX(chunk + 1, xb ^ 1);  // 9 taps of flight
            const int kh = pos / 3, kw = pos - kh * 3;
            const int xr = wn + kh;
#pragma unroll
            for (int s = 0; s < 2; ++s) {
                const int cg = s * 4 + quad;
                bf16x8 bfr[4];
#pragma unroll
                for (int nt = 0; nt < 4; ++nt)
                    bfr[nt] = *(const bf16x8*)&Xs[xb][xr][cg][kw + nt * 16 + lane15][0];
#pragma unroll
                for (int mt = 0; mt < 4; ++mt)
#pragma unroll
                    for (int nt = 0; nt < 4; ++nt)
                        acc[mt][nt] = __builtin_amdgcn_mfma_f32_16x16x32_bf16(
                            afr[par][s * 4 + mt], bfr[nt], acc[mt][nt], 0, 0, 0);
            }
        }
        if (chunk < 3) __syncthreads();  // readers of Xs[xb] done; next-X DMA drained
    }

    // epilogue: conv + agg_b + residual, fp32 out
    const int y = ytile * 2 + wn;
#pragma unroll
    for (int mt = 0; mt < 4; ++mt) {
#pragma unroll
        for (int r = 0; r < 4; ++r) {
            const int co = half * 128 + wm * 64 + mt * 16 + quad * 4 + r;
            const float bbv = aggb[b * 256 + co];
            const size_t rowbase = (((size_t)b * 256 + co) * 64 + y) * 64;
#pragma unroll
            for (int nt = 0; nt < 4; ++nt) {
                const size_t oidx = rowbase + nt * 16 + lane15;
                out[oidx] = acc[mt][nt][r] + bbv + xin[oidx];
            }
        }
    }
}

// ---------------------------------------------------------------------------
extern "C" void kernel_launch(void* const* d_in, const int* in_sizes, int n_in,
                              void* d_out, int out_size, void* d_ws, size_t ws_size,
                              hipStream_t stream) {
    const float* x    = (const float*)d_in[0];  // [8,256,64,64]
    const float* sk   = (const float*)d_in[1];  // [8,1,56,56]
    const float* wgt  = (const float*)d_in[2];  // [16,256,256,3,3]
    const float* bias = (const float*)d_in[3];  // [16,256]
    const float* w1   = (const float*)d_in[4];  // [196,784]
    const float* w2   = (const float*)d_in[5];  // [16,196]
    float* out = (float*)d_out;

    char* ws = (char*)d_ws;
    float* att  = (float*)(ws + 0);                      // 512 B
    float* aggb = (float*)(ws + 1024);                   // 8 KB
    bf16*  aggw = (bf16*)(ws + 16384);                   // 9,437,184 B
    bf16*  xt   = (bf16*)(ws + 16384 + 9437184);         // 16,777,216 B

    prep_kernel<<<520, 256, 0, stream>>>(x, xt, sk, w1, w2, att);
    agg_kernel<<<1024, 256, 0, stream>>>(wgt, bias, att, aggw, aggb);
    conv_kernel<<<512, 256, 0, stream>>>(xt, aggw, aggb, x, out);
}